// Round 3
// baseline (217.293 us; speedup 1.0000x reference)
//
#include <hip/hip_runtime.h>
#include <math.h>

// Problem constants (B,L,H,D) = (2,4096,8,64); sample_k = n_top = 45
#define B_ 2
#define L_ 4096
#define H_ 8
#define D_ 64
#define S_ 45
#define NTOP_ 45
#define SCALE 0.125f  // 1/sqrt(64)
#define TKEYS 64      // keys per attn block
#define NSPLIT 64     // key splits per (b,h)
#define NCAND (16 * NTOP_)   // 720 merge candidates per bh

// DPP helper: move with compile-time ctrl (quad_perm patterns, butterfly-safe).
template<int CTRL>
__device__ __forceinline__ float dpp_permf(float x) {
    return __int_as_float(__builtin_amdgcn_update_dpp(
        0, __float_as_int(x), CTRL, 0xF, 0xF, true));
}

// ---------------- K1: sparsity measure M = max_s(q.k_s) - sum_s/L ----------------
// At the L2 random-gather LINE-RATE ceiling — confirmed across 5 layouts (r1:
// head-pair contiguity halved segment count, duration flat at 42us; binding
// resource is 64B lines/cyc, ~0.49 lines/cy/CU). The key-major dual has identical
// line traffic (each key row serves ~45 random q rows instead) — no reformulation
// reduces touch bytes while K-per-bh (1MB) exceeds LDS. DO NOT add work here:
// streaming writes through L2 risks evicting the hot K slice (19MB FETCH would grow).
__global__ __launch_bounds__(256) void compute_M_kernel(
    const float* __restrict__ q, const float* __restrict__ k,
    const int* __restrict__ samp, float* __restrict__ M) {
    __shared__ int sIdx[8 * 48];    // 8 queries x 45 idx + 3 pad
    int tid = threadIdx.x;
    int g   = blockIdx.x;           // 0..4095
    int xcd = g & 7;                // slice id: b = xcd>>2, head-pair = xcd&3
    int chunk = g >> 3;             // 0..511 -> 8 queries each
    int b  = xcd >> 2;
    int h0 = (xcd & 3) * 2;
    int l0 = chunk * 8;

    for (int i = tid; i < 8 * S_; i += 256) {
        int qq = i / S_, ss = i - qq * S_;
        sIdx[qq * 48 + ss] = samp[(long)(l0 + qq) * S_ + ss];
    }
    if (tid < 24) sIdx[(tid / 3) * 48 + S_ + (tid % 3)] = 0;  // pad slots 45..47
    __syncthreads();

    int lane = tid & 63, wave = tid >> 6;
    int c  = lane & 31;             // float4 slot within 512B row-pair
    int q8 = wave * 2 + (lane >> 5);
    int l  = l0 + q8;

    float4 q4 = ((const float4*)(q + (((long)(b * L_ + l)) * H_ + h0) * D_))[c];
    const float4* kb4 = (const float4*)(k + ((long)b * L_ * H_ + h0) * (long)D_);
    const int* myIdx = sIdx + q8 * 48;

    float4 f0 = kb4[(long)myIdx[0] * 128 + c];
    float4 f1 = kb4[(long)myIdx[1] * 128 + c];
    float4 f2 = kb4[(long)myIdx[2] * 128 + c];

    float vmax = -INFINITY, vsum = 0.f;
    #pragma unroll 3
    for (int s = 0; s < S_; ++s) {
        float4 nf = kb4[(long)myIdx[s + 3] * 128 + c];
        float p = q4.x * f0.x + q4.y * f0.y + q4.z * f0.z + q4.w * f0.w;
        p += dpp_permf<0xB1>(p);        // quad_perm xor 1 (VALU pipe)
        p += dpp_permf<0x4E>(p);        // quad_perm xor 2 (VALU pipe)
        p += __shfl_xor(p, 4, 64);
        p += __shfl_xor(p, 8, 64);
        vmax = fmaxf(vmax, p);
        vsum += p;
        f0 = f1; f1 = f2; f2 = nf;
    }
    if ((lane & 15) == 0) {
        int h = h0 + ((lane >> 4) & 1);
        M[(long)(b * 8 + h) * L_ + l] = vmax - vsum * (1.0f / (float)L_);
    }
}

// ---------------- K2: per-chunk top-45 candidates + fused output zeroing ----------------
// 256 blocks, one per (bh, 256-l chunk). Composite key = (monotone_bits<<32) |
// (0xFFFFFFFF - l): unique, value-desc then lowest-index — matches top_k ties.
// Global top-45 of a bh is contained in the union of its 16 chunk top-45 sets.
// Fused: zero the 16MB output here (256 parallel short blocks hide 2.5us of
// write BW; keeps it OUT of K1's L2 working set and out of K4's critical path).
__global__ __launch_bounds__(256) void chunk_topk_kernel(
    const float* __restrict__ M, unsigned long long* __restrict__ cand,
    float* __restrict__ out) {
    __shared__ unsigned long long sKey[256];
    int g = blockIdx.x;             // bh*16 + chunk
    int bh = g >> 4, chunk = g & 15;
    int tid = threadIdx.x;

    // fused zero: block g covers out float4s [g*4096, (g+1)*4096)
    float4 z = make_float4(0.f, 0.f, 0.f, 0.f);
    float4* obase = (float4*)out + (long)g * 4096 + tid;
    #pragma unroll
    for (int j = 0; j < 16; ++j) obase[j * 256] = z;

    int l = chunk * 256 + tid;
    unsigned int bts = __float_as_uint(M[(long)bh * L_ + l]);
    unsigned int mapped = bts ^ ((unsigned int)((int)bts >> 31) | 0x80000000u);
    unsigned long long key =
        ((unsigned long long)mapped << 32) | (unsigned long long)(0xFFFFFFFFu - (unsigned int)l);
    sKey[tid] = key;
    __syncthreads();
    int rank = 0;
    #pragma unroll 16
    for (int j = 0; j < 256; ++j)
        rank += (sKey[j] > key) ? 1 : 0;       // LDS broadcast reads, conflict-free
    if (rank < NTOP_)
        cand[((long)bh * 16 + chunk) * NTOP_ + rank] = key;
}

// Inline merge: 720 candidate keys (LDS) -> sTop[0..44] = selected l, rank order.
// ~720 broadcast b64 reads per thread (3 keys ranked in one scan), ~1us, overlapped.
__device__ __forceinline__ void merge_topk_inline(
    const unsigned long long* __restrict__ cand, int bh, int tid,
    unsigned long long* sKey, int* sTop) {
    for (int i = tid; i < NCAND; i += 256)
        sKey[i] = cand[(long)bh * NCAND + i];
    __syncthreads();
    unsigned long long k0 = sKey[tid];
    unsigned long long k1 = sKey[tid + 256];
    bool has2 = (tid + 512) < NCAND;
    unsigned long long k2 = has2 ? sKey[tid + 512] : 0ull;
    int r0 = 0, r1 = 0, r2 = 0;
    #pragma unroll 8
    for (int j = 0; j < NCAND; ++j) {
        unsigned long long kj = sKey[j];
        r0 += (kj > k0) ? 1 : 0;
        r1 += (kj > k1) ? 1 : 0;
        r2 += (kj > k2) ? 1 : 0;
    }
    if (r0 < NTOP_) sTop[r0] = (int)(0xFFFFFFFFu - (unsigned int)(k0 & 0xFFFFFFFFull));
    if (r1 < NTOP_) sTop[r1] = (int)(0xFFFFFFFFu - (unsigned int)(k1 & 0xFFFFFFFFull));
    if (has2 && r2 < NTOP_) sTop[r2] = (int)(0xFFFFFFFFu - (unsigned int)(k2 & 0xFFFFFFFFull));
    __syncthreads();
}

// ---------------- K3: key-strip attention with inline candidate merge ----------------
#define STRIDE 68
__global__ __launch_bounds__(256, 2) void attn_strip_kernel(
    const float* __restrict__ q, const float* __restrict__ k,
    const float* __restrict__ v, const unsigned long long* __restrict__ cand,
    float* __restrict__ pOut, float* __restrict__ plPart, int nsplit) {
    __shared__ float sQ[48 * STRIDE];     // 13.1 KB
    __shared__ float sK[TKEYS * STRIDE];  // 17.4 KB
    __shared__ float sV[TKEYS * STRIDE];  // 17.4 KB
    __shared__ float sP[48 * STRIDE];     // 13.1 KB
    __shared__ unsigned long long sKey[NCAND];  // 5.8 KB
    __shared__ int sTop[48];

    int g = blockIdx.x;
    int xcd = g & 7;
    int s0 = g >> 3;
    int grp = s0 / nsplit;
    int bh = xcd + 8 * grp;
    int split = s0 - grp * nsplit;
    int b = bh >> 3, h = bh & 7;
    int tid = threadIdx.x;
    int key0 = split * TKEYS;

    // K and V loads first (no dependency on merge; latency overlaps merge compute)
    #pragma unroll
    for (int j = 0; j < 4; ++j) {
        int i = tid + 256 * j;
        int r = i >> 4, d4 = i & 15;
        long off = (((long)(b * L_ + key0 + r)) * H_ + h) * D_ + 4 * d4;
        *(float4*)(sK + r * STRIDE + 4 * d4) = *(const float4*)(k + off);
        *(float4*)(sV + r * STRIDE + 4 * d4) = *(const float4*)(v + off);
    }

    merge_topk_inline(cand, bh, tid, sKey, sTop);

    // Q gather via sTop
    #pragma unroll
    for (int j = 0; j < 3; ++j) {
        int i = tid + 256 * j;
        int u = i >> 4, d4 = i & 15;
        float4 val = make_float4(0.f, 0.f, 0.f, 0.f);
        if (u < NTOP_) {
            int lq = sTop[u];
            val = *(const float4*)(q + (((long)(b * L_ + lq)) * H_ + h) * D_ + 4 * d4);
        }
        *(float4*)(sQ + u * STRIDE + 4 * d4) = val;
    }
    __syncthreads();

    int tx = tid & 15, ty = tid >> 4;
    float acc[3][4];
    #pragma unroll
    for (int i = 0; i < 3; ++i)
        #pragma unroll
        for (int j = 0; j < 4; ++j) acc[i][j] = 0.f;

    #pragma unroll 4
    for (int d4 = 0; d4 < 16; ++d4) {
        float4 qv[3];
        #pragma unroll
        for (int i = 0; i < 3; ++i)
            qv[i] = *(const float4*)(sQ + (3 * ty + i) * STRIDE + 4 * d4);
        #pragma unroll
        for (int j = 0; j < 4; ++j) {
            float4 kv = *(const float4*)(sK + (tx + 16 * j) * STRIDE + 4 * d4);
            #pragma unroll
            for (int i = 0; i < 3; ++i)
                acc[i][j] += qv[i].x * kv.x + qv[i].y * kv.y + qv[i].z * kv.z + qv[i].w * kv.w;
        }
    }
    #pragma unroll
    for (int i = 0; i < 3; ++i) {
        #pragma unroll
        for (int j = 0; j < 4; ++j)
            sP[(3 * ty + i) * STRIDE + tx + 16 * j] = __expf(acc[i][j] * SCALE);
    }
    __syncthreads();

    int dx = tid & 15, uy = tid >> 4;
    float o[3][4];
    float ls[3];
    #pragma unroll
    for (int i = 0; i < 3; ++i) {
        ls[i] = 0.f;
        #pragma unroll
        for (int c = 0; c < 4; ++c) o[i][c] = 0.f;
    }
    #pragma unroll 4
    for (int k4 = 0; k4 < 16; ++k4) {
        float pa[3][4];
        #pragma unroll
        for (int i = 0; i < 3; ++i)
            *(float4*)pa[i] = *(const float4*)(sP + (3 * uy + i) * STRIDE + 4 * k4);
        #pragma unroll
        for (int c = 0; c < 4; ++c) {
            float4 vr = *(const float4*)(sV + (4 * k4 + c) * STRIDE + 4 * dx);
            #pragma unroll
            for (int i = 0; i < 3; ++i) {
                o[i][0] += pa[i][c] * vr.x;
                o[i][1] += pa[i][c] * vr.y;
                o[i][2] += pa[i][c] * vr.z;
                o[i][3] += pa[i][c] * vr.w;
                ls[i]   += pa[i][c];
            }
        }
    }
    #pragma unroll
    for (int i = 0; i < 3; ++i) {
        int u = 3 * uy + i;
        if (u < NTOP_) {
            long base = ((long)(split * 16 + bh) * NTOP_ + u) * D_;
            *(float4*)(pOut + base + 4 * dx) = make_float4(o[i][0], o[i][1], o[i][2], o[i][3]);
            if (dx == 0) plPart[(long)(split * 16 + bh) * NTOP_ + u] = ls[i];
        }
    }
}

// ---------------- K4: slim reduce + normalize + scatter (zeroing done in K2) ----------------
// 64 blocks = (bh, row-group of 12). Inline merge gives row index; one wave per
// row, lane = d: coalesced 256B reads across nsplit partials.
__global__ __launch_bounds__(256) void reduce_scatter_kernel(
    const unsigned long long* __restrict__ cand, const float* __restrict__ pOut,
    const float* __restrict__ plPart, float* __restrict__ out, int nsplit) {
    __shared__ unsigned long long sKey[NCAND];
    __shared__ int sTop[48];
    int g = blockIdx.x;               // bh*4 + rg
    int bh = g >> 2, rg = g & 3;
    int b = bh >> 3, h = bh & 7;
    int tid = threadIdx.x;

    merge_topk_inline(cand, bh, tid, sKey, sTop);

    int lane = tid & 63, wave = tid >> 6;
    #pragma unroll
    for (int it = 0; it < 3; ++it) {
        int u = rg * 12 + it * 4 + wave;
        if (u >= NTOP_ || u >= rg * 12 + 12) continue;
        // l-sum across splits: lane s holds partial s, butterfly to all lanes
        float lv = (lane < nsplit) ? plPart[((long)lane * 16 + bh) * NTOP_ + u] : 0.f;
        #pragma unroll
        for (int o = 32; o > 0; o >>= 1) lv += __shfl_xor(lv, o, 64);
        float accv = 0.f;
        const float* pb = pOut + ((long)bh * NTOP_ + u) * D_ + lane;
        #pragma unroll 8
        for (int s = 0; s < nsplit; ++s) accv += pb[(long)s * 16 * NTOP_ * D_];
        int l = sTop[u];
        out[(((long)(b * L_ + l)) * H_ + h) * D_ + lane] = accv / lv;
    }
}

extern "C" void kernel_launch(void* const* d_in, const int* in_sizes, int n_in,
                              void* d_out, int out_size, void* d_ws, size_t ws_size,
                              hipStream_t stream) {
    const float* q = (const float*)d_in[0];
    const float* k = (const float*)d_in[1];
    const float* v = (const float*)d_in[2];
    // d_in[3] = attn_mask (unused)
    const int* samp = (const int*)d_in[4];
    float* out = (float*)d_out;

    char* ws = (char*)d_ws;
    const size_t mBytes    = (size_t)B_ * H_ * L_ * sizeof(float);     // 512 KB
    const size_t plBytes   = (size_t)NSPLIT * 16 * NTOP_ * sizeof(float);
    const size_t poutBytes = (size_t)NSPLIT * 16 * NTOP_ * D_ * sizeof(float);
    const size_t candBytes = (size_t)B_ * H_ * NCAND * sizeof(unsigned long long);
    float* M      = (float*)ws;
    float* plPart = (float*)(ws + mBytes);
    float* pOut   = (float*)(ws + mBytes + plBytes);
    unsigned long long* cand =
        (unsigned long long*)(ws + mBytes + plBytes + poutBytes);

    int nsplit = NSPLIT;
    while (nsplit > 1) {
        size_t need = mBytes + plBytes + candBytes +
                      (size_t)nsplit * 16 * NTOP_ * D_ * sizeof(float);
        if (need <= ws_size) break;
        nsplit >>= 1;
    }

    compute_M_kernel<<<4096, 256, 0, stream>>>(q, k, samp, M);

    chunk_topk_kernel<<<B_ * H_ * 16, 256, 0, stream>>>(M, cand, out);

    attn_strip_kernel<<<nsplit * B_ * H_, 256, 0, stream>>>(
        q, k, v, cand, pOut, plPart, nsplit);

    reduce_scatter_kernel<<<B_ * H_ * 4, 256, 0, stream>>>(
        cand, pOut, plPart, out, nsplit);
}

// Round 4
// 155.333 us; speedup vs baseline: 1.3989x; 1.3989x over previous
//
#include <hip/hip_runtime.h>
#include <math.h>

// Problem constants (B,L,H,D) = (2,4096,8,64); sample_k = n_top = 45
#define B_ 2
#define L_ 4096
#define H_ 8
#define D_ 64
#define S_ 45
#define NTOP_ 45
#define SCALE 0.125f  // 1/sqrt(64)
#define TKEYS 64      // keys per attn block
#define NSPLIT 64     // key splits per (b,h)

// DPP helper: move with compile-time ctrl (quad_perm patterns, butterfly-safe).
template<int CTRL>
__device__ __forceinline__ float dpp_permf(float x) {
    return __int_as_float(__builtin_amdgcn_update_dpp(
        0, __float_as_int(x), CTRL, 0xF, 0xF, true));
}

// ---------------- K1: sparsity measure M = max_s(q.k_s) - sum_s/L ----------------
// At the L2 random-gather LINE-RATE ceiling — confirmed across 5 layouts (r1:
// head-pair contiguity halved segment count, duration flat 42us). Binding resource
// is 64B lines/cyc. DO NOT add work or change layout here.
__global__ __launch_bounds__(256) void compute_M_kernel(
    const float* __restrict__ q, const float* __restrict__ k,
    const int* __restrict__ samp, float* __restrict__ M) {
    __shared__ int sIdx[8 * 48];    // 8 queries x 45 idx + 3 pad
    int tid = threadIdx.x;
    int g   = blockIdx.x;           // 0..4095
    int xcd = g & 7;                // slice id: b = xcd>>2, head-pair = xcd&3
    int chunk = g >> 3;             // 0..511 -> 8 queries each
    int b  = xcd >> 2;
    int h0 = (xcd & 3) * 2;
    int l0 = chunk * 8;

    for (int i = tid; i < 8 * S_; i += 256) {
        int qq = i / S_, ss = i - qq * S_;
        sIdx[qq * 48 + ss] = samp[(long)(l0 + qq) * S_ + ss];
    }
    if (tid < 24) sIdx[(tid / 3) * 48 + S_ + (tid % 3)] = 0;  // pad slots 45..47
    __syncthreads();

    int lane = tid & 63, wave = tid >> 6;
    int c  = lane & 31;             // float4 slot within 512B row-pair
    int q8 = wave * 2 + (lane >> 5);
    int l  = l0 + q8;

    float4 q4 = ((const float4*)(q + (((long)(b * L_ + l)) * H_ + h0) * D_))[c];
    const float4* kb4 = (const float4*)(k + ((long)b * L_ * H_ + h0) * (long)D_);
    const int* myIdx = sIdx + q8 * 48;

    float4 f0 = kb4[(long)myIdx[0] * 128 + c];
    float4 f1 = kb4[(long)myIdx[1] * 128 + c];
    float4 f2 = kb4[(long)myIdx[2] * 128 + c];

    float vmax = -INFINITY, vsum = 0.f;
    #pragma unroll 3
    for (int s = 0; s < S_; ++s) {
        float4 nf = kb4[(long)myIdx[s + 3] * 128 + c];
        float p = q4.x * f0.x + q4.y * f0.y + q4.z * f0.z + q4.w * f0.w;
        p += dpp_permf<0xB1>(p);        // quad_perm xor 1 (VALU pipe)
        p += dpp_permf<0x4E>(p);        // quad_perm xor 2 (VALU pipe)
        p += __shfl_xor(p, 4, 64);
        p += __shfl_xor(p, 8, 64);
        vmax = fmaxf(vmax, p);
        vsum += p;
        f0 = f1; f1 = f2; f2 = nf;
    }
    if ((lane & 15) == 0) {
        int h = h0 + ((lane >> 4) & 1);
        M[(long)(b * 8 + h) * L_ + l] = vmax - vsum * (1.0f / (float)L_);
    }
}

// ---------------- K2: top-45 set per (b,h) via byte-radix select (r0-proven) ----------------
// 16 blocks. Measured ≲10us in the r0 config (cross-round ledger r1->r2: replacing
// it with chunk+merge cost +9us). Output order arbitrary: reference scatters
// context row u to M_top[u], so only the selected SET matters. Ties -> lowest index.
__global__ __launch_bounds__(256) void topk_kernel(
    const float* __restrict__ M, int* __restrict__ topIdx) {
    __shared__ unsigned int hist[256];
    __shared__ unsigned int suf[257];
    __shared__ unsigned int wsum[4];
    __shared__ int sBin, sRemain, sCnt, sTieCnt;
    __shared__ int tie[64];

    int bh = blockIdx.x, tid = threadIdx.x;
    int lane = tid & 63, wave = tid >> 6;
    const float* row = M + (long)bh * L_;

    unsigned int key[16];
    #pragma unroll
    for (int j = 0; j < 16; ++j) {
        unsigned int bts = __float_as_uint(row[tid + 256 * j]);
        key[j] = bts ^ ((unsigned int)((int)bts >> 31) | 0x80000000u);
    }

    unsigned int prefix = 0, pmask = 0;
    int remain = NTOP_;
    #pragma unroll 1
    for (int pass = 3; pass >= 0; --pass) {
        int shift = pass * 8;
        hist[tid] = 0;
        __syncthreads();
        #pragma unroll
        for (int j = 0; j < 16; ++j) {
            if ((key[j] & pmask) == prefix)
                atomicAdd(&hist[(key[j] >> shift) & 255u], 1u);
        }
        __syncthreads();
        unsigned int s = hist[tid];
        #pragma unroll
        for (int off = 1; off < 64; off <<= 1) {
            unsigned int o = __shfl_down(s, off, 64);
            if (lane + off < 64) s += o;
        }
        if (lane == 0) wsum[wave] = s;
        __syncthreads();
        unsigned int add = 0;
        for (int w = wave + 1; w < 4; ++w) add += wsum[w];
        s += add;
        suf[tid] = s;
        if (tid == 0) suf[256] = 0;
        __syncthreads();
        if (suf[tid] >= (unsigned int)remain && suf[tid + 1] < (unsigned int)remain) {
            sBin = tid;
            sRemain = remain - (int)suf[tid + 1];
        }
        __syncthreads();
        prefix |= ((unsigned int)sBin) << shift;
        pmask  |= 0xFFu << shift;
        remain  = sRemain;
        __syncthreads();
    }

    if (tid == 0) { sCnt = 0; sTieCnt = 0; }
    __syncthreads();
    int* outRow = topIdx + bh * NTOP_;
    #pragma unroll
    for (int j = 0; j < 16; ++j) {
        int idx = tid + 256 * j;
        if (key[j] > prefix) {
            int pos = atomicAdd(&sCnt, 1);
            outRow[pos] = idx;
        } else if (key[j] == prefix) {
            int tp = atomicAdd(&sTieCnt, 1);
            if (tp < 64) tie[tp] = idx;
        }
    }
    __syncthreads();
    if (tid == 0) {
        int base = sCnt;
        int tc = sTieCnt < 64 ? sTieCnt : 64;
        for (int t = 0; t < remain; ++t) {
            int mi = 0x7fffffff, mj = 0;
            for (int j2 = 0; j2 < tc; ++j2)
                if (tie[j2] < mi) { mi = tie[j2]; mj = j2; }
            outRow[base + t] = mi;
            tie[mj] = 0x7fffffff;
        }
    }
}

// ---------------- K3: key-strip attention (r0 form) + fused output zeroing ----------------
// r0-proven structure: topIdx read direct (L2-hot, 16 blocks wrote it), no merge,
// LDS 61KB, 2 blocks/CU. NEW (cheap fusion): each of the 1024 blocks zeroes a
// disjoint 16KB slice of out (4 coalesced float4 stores/thread, ~2.6us write BW
// hidden under compute) -> memset dispatch eliminated. Stream order guarantees
// zeros land before K4's scatter.
#define STRIDE 68
__global__ __launch_bounds__(256, 2) void attn_strip_kernel(
    const float* __restrict__ q, const float* __restrict__ k,
    const float* __restrict__ v, const int* __restrict__ topIdx,
    float* __restrict__ pOut, float* __restrict__ plPart,
    float* __restrict__ out, int nsplit) {
    __shared__ float sQ[48 * STRIDE];     // 13.1 KB
    __shared__ float sK[TKEYS * STRIDE];  // 17.4 KB
    __shared__ float sV[TKEYS * STRIDE];  // 17.4 KB
    __shared__ float sP[48 * STRIDE];     // 13.1 KB

    int g = blockIdx.x;
    int xcd = g & 7;
    int s0 = g >> 3;
    int grp = s0 / nsplit;
    int bh = xcd + 8 * grp;
    int split = s0 - grp * nsplit;
    int b = bh >> 3, h = bh & 7;
    int tid = threadIdx.x;
    int key0 = split * TKEYS;

    // ---- issue ALL global loads up front (r0 pattern) ----
    #pragma unroll
    for (int j = 0; j < 3; ++j) {
        int i = tid + 256 * j;
        int u = i >> 4, d4 = i & 15;
        float4 val = make_float4(0.f, 0.f, 0.f, 0.f);
        if (u < NTOP_) {
            int lq = topIdx[bh * NTOP_ + u];
            val = *(const float4*)(q + (((long)(b * L_ + lq)) * H_ + h) * D_ + 4 * d4);
        }
        *(float4*)(sQ + u * STRIDE + 4 * d4) = val;
    }
    #pragma unroll
    for (int j = 0; j < 4; ++j) {
        int i = tid + 256 * j;
        int r = i >> 4, d4 = i & 15;
        long off = (((long)(b * L_ + key0 + r)) * H_ + h) * D_ + 4 * d4;
        *(float4*)(sK + r * STRIDE + 4 * d4) = *(const float4*)(k + off);
        *(float4*)(sV + r * STRIDE + 4 * d4) = *(const float4*)(v + off);
    }

    // fused zero of this block's out slice (fire-and-forget stores)
    {
        long total4 = (long)B_ * L_ * H_ * D_ / 4;       // 1,048,576 float4
        long per = total4 / ((long)nsplit * 16);         // 1024 at nsplit=64
        float4* ob = (float4*)out + (long)g * per;
        float4 z = make_float4(0.f, 0.f, 0.f, 0.f);
        for (long j = tid; j < per; j += 256) ob[j] = z;
    }
    __syncthreads();

    // ---- S phase: thread (ty,tx): u = 3ty+i (i<3) x keys tx+16j (j<4) ----
    int tx = tid & 15, ty = tid >> 4;
    float acc[3][4];
    #pragma unroll
    for (int i = 0; i < 3; ++i)
        #pragma unroll
        for (int j = 0; j < 4; ++j) acc[i][j] = 0.f;

    #pragma unroll 4
    for (int d4 = 0; d4 < 16; ++d4) {
        float4 qv[3];
        #pragma unroll
        for (int i = 0; i < 3; ++i)
            qv[i] = *(const float4*)(sQ + (3 * ty + i) * STRIDE + 4 * d4);
        #pragma unroll
        for (int j = 0; j < 4; ++j) {
            float4 kv = *(const float4*)(sK + (tx + 16 * j) * STRIDE + 4 * d4);
            #pragma unroll
            for (int i = 0; i < 3; ++i)
                acc[i][j] += qv[i].x * kv.x + qv[i].y * kv.y + qv[i].z * kv.z + qv[i].w * kv.w;
        }
    }
    #pragma unroll
    for (int i = 0; i < 3; ++i) {
        #pragma unroll
        for (int j = 0; j < 4; ++j)
            sP[(3 * ty + i) * STRIDE + tx + 16 * j] = __expf(acc[i][j] * SCALE);
    }
    __syncthreads();

    // ---- PV phase: thread (uy,dx): u = 3uy+i (i<3) x d = 4dx..4dx+3 ----
    int dx = tid & 15, uy = tid >> 4;
    float o[3][4];
    float ls[3];
    #pragma unroll
    for (int i = 0; i < 3; ++i) {
        ls[i] = 0.f;
        #pragma unroll
        for (int c = 0; c < 4; ++c) o[i][c] = 0.f;
    }
    #pragma unroll 4
    for (int k4 = 0; k4 < 16; ++k4) {
        float pa[3][4];
        #pragma unroll
        for (int i = 0; i < 3; ++i)
            *(float4*)pa[i] = *(const float4*)(sP + (3 * uy + i) * STRIDE + 4 * k4);
        #pragma unroll
        for (int c = 0; c < 4; ++c) {
            float4 vr = *(const float4*)(sV + (4 * k4 + c) * STRIDE + 4 * dx);
            #pragma unroll
            for (int i = 0; i < 3; ++i) {
                o[i][0] += pa[i][c] * vr.x;
                o[i][1] += pa[i][c] * vr.y;
                o[i][2] += pa[i][c] * vr.z;
                o[i][3] += pa[i][c] * vr.w;
                ls[i]   += pa[i][c];
            }
        }
    }
    #pragma unroll
    for (int i = 0; i < 3; ++i) {
        int u = 3 * uy + i;
        if (u < NTOP_) {
            long base = ((long)(split * 16 + bh) * NTOP_ + u) * D_;
            *(float4*)(pOut + base + 4 * dx) = make_float4(o[i][0], o[i][1], o[i][2], o[i][3]);
            if (dx == 0) plPart[(long)(split * 16 + bh) * NTOP_ + u] = ls[i];
        }
    }
}

// ---------------- K4: reduce partials across splits, normalize, scatter (r0 form) ----------------
__global__ __launch_bounds__(256) void reduce_norm_kernel(
    const int* __restrict__ topIdx, const float* __restrict__ pOut,
    const float* __restrict__ plPart, float* __restrict__ out, int nsplit) {
    __shared__ float part[4][64];
    __shared__ float lpart[4];
    int u = blockIdx.x, bh = blockIdx.y;
    int b = bh >> 3, h = bh & 7;
    int tid = threadIdx.x;
    int d = tid & 63, sg = tid >> 6;
    float acc = 0.f, lsum = 0.f;
    for (int s = sg; s < nsplit; s += 4) {
        acc  += pOut[((long)(s * 16 + bh) * NTOP_ + u) * D_ + d];
        lsum += plPart[(long)(s * 16 + bh) * NTOP_ + u];
    }
    part[sg][d] = acc;
    if (d == 0) lpart[sg] = lsum;
    __syncthreads();
    if (sg == 0) {
        float a = part[0][d] + part[1][d] + part[2][d] + part[3][d];
        float lt = lpart[0] + lpart[1] + lpart[2] + lpart[3];
        int lq = topIdx[bh * NTOP_ + u];
        out[(((long)(b * L_ + lq)) * H_ + h) * D_ + d] = a / lt;
    }
}

extern "C" void kernel_launch(void* const* d_in, const int* in_sizes, int n_in,
                              void* d_out, int out_size, void* d_ws, size_t ws_size,
                              hipStream_t stream) {
    const float* q = (const float*)d_in[0];
    const float* k = (const float*)d_in[1];
    const float* v = (const float*)d_in[2];
    // d_in[3] = attn_mask (unused)
    const int* samp = (const int*)d_in[4];
    float* out = (float*)d_out;

    char* ws = (char*)d_ws;
    const size_t mBytes   = (size_t)B_ * H_ * L_ * sizeof(float);   // 512 KB
    const size_t topBytes = (size_t)B_ * H_ * NTOP_ * sizeof(int);  // 2880 B
    const size_t plBytes  = (size_t)NSPLIT * 16 * NTOP_ * sizeof(float);
    float* M      = (float*)ws;
    int*   topIdx = (int*)(ws + mBytes);
    float* plPart = (float*)(ws + mBytes + topBytes);
    float* pOut   = (float*)(ws + mBytes + topBytes + plBytes);

    int nsplit = NSPLIT;
    while (nsplit > 1) {
        size_t need = mBytes + topBytes + plBytes +
                      (size_t)nsplit * 16 * NTOP_ * D_ * sizeof(float);
        if (need <= ws_size) break;
        nsplit >>= 1;
    }

    compute_M_kernel<<<4096, 256, 0, stream>>>(q, k, samp, M);

    topk_kernel<<<B_ * H_, 256, 0, stream>>>(M, topIdx);

    attn_strip_kernel<<<nsplit * B_ * H_, 256, 0, stream>>>(
        q, k, v, topIdx, pOut, plPart, out, nsplit);

    dim3 gn(NTOP_, B_ * H_);
    reduce_norm_kernel<<<gn, 256, 0, stream>>>(topIdx, pOut, plPart, out, nsplit);
}